// Round 6
// baseline (2063.007 us; speedup 1.0000x reference)
//
#include <hip/hip_runtime.h>

typedef unsigned short u16;
typedef unsigned int   u32;
typedef short v8s   __attribute__((ext_vector_type(8)));
typedef float f32x4 __attribute__((ext_vector_type(4)));
typedef float f32x2 __attribute__((ext_vector_type(2)));

#define H_ 256
#define B_ 8192
#define NSTEP 31
#define NTHREADS 512
#define NBLOCKS 256
#define AROW 264   // 256+8 u16 pad: 528B rows

#define MFMA16(a,b,c) __builtin_amdgcn_mfma_f32_16x16x32_bf16(a,b,c,0,0,0)

#define DPP_QP_XOR1 0xB1
#define DPP_QP_XOR2 0x4E
#define DPP_ROR4    0x124
#define DPP_ROR8    0x128

template<int CTRL>
__device__ __forceinline__ float dpp_add(float v){
  return v + __int_as_float(__builtin_amdgcn_update_dpp(0, __float_as_int(v), CTRL, 0xF, 0xF, true));
}
template<int CTRL>
__device__ __forceinline__ u32 dpp_movu(u32 v){
  return (u32)__builtin_amdgcn_update_dpp(0, (int)v, CTRL, 0xF, 0xF, true);
}
__device__ __forceinline__ u32 permb(u32 a, u32 b, u32 sel){
  return __builtin_amdgcn_perm(a, b, sel);
}
__device__ __forceinline__ u16 f2bf_rne(float f){
  unsigned u = __float_as_uint(f);
  u += 0x7fffu + ((u >> 16) & 1u);
  return (u16)(u >> 16);
}

// ---- workspace (u16 units) ----
#define WS_W0   0        // [q][n][j] 4*256*8 = 8192 (K-pad to 32; k==6 row = b0)
#define WS_W1   8192     // [n][k]   256*256 = 65536 (Wh[0] transposed)
#define WS_W23  73728    // [l][q][col][kc][j] 2*4*256*64 = 131072
#define WS_TOT  204800

__global__ void prep_kernel(const float* __restrict__ W0,
                            const float* __restrict__ b0,
                            const float* __restrict__ Wh,
                            u16* __restrict__ ws){
  int i = blockIdx.x * 256 + threadIdx.x;
  if (i < 8192){
    int q = i >> 11, n = (i >> 3) & 255, j = i & 7;
    int k = q*8 + j;
    float v = (k < 6) ? W0[k*H_ + n] : ((k == 6) ? b0[n] : 0.f);
    ws[i] = f2bf_rne(v);
  } else if (i < 73728){
    int r = i - 8192;
    int n = r >> 8, k = r & 255;
    ws[i] = f2bf_rne(Wh[k*H_ + n]);
  } else if (i < WS_TOT){
    int r = i - 73728;
    int j = r & 7, kc = (r >> 3) & 7, col = (r >> 6) & 255;
    int q = (r >> 14) & 3, l = (r >> 16) & 1;
    int k = kc*32 + q*8 + j;
    ws[i] = f2bf_rne(Wh[(1 + l)*H_*H_ + k*H_ + col]);
  }
}

// ---- LDS (bytes) ----
#define PWF 20
#define OFF_A      0        // 16896
#define OFF_W1     16896    // 135168
#define OFF_PART   152064   // 32*PWF*4 = 2560
#define OFF_NETP   154624   // 8*32*16 = 4096
#define OFF_MRS    158720   // 8 waves * 32 rows * 8B = 2048
#define OFF_DTS    160768   // 128
#define LDS_TOTAL  160896

__global__ __launch_bounds__(NTHREADS, 2)
void pinode_kernel(const float* __restrict__ y0g, const float* __restrict__ t_span,
                   const float* __restrict__ params, const float* __restrict__ bhg,
                   const float* __restrict__ ln_gg, const float* __restrict__ ln_bg,
                   const float* __restrict__ boutg, const float* __restrict__ gatep,
                   const float* __restrict__ Woutg, const u16* __restrict__ ws,
                   float* __restrict__ out)
{
  extern __shared__ char smem[];
  u16*   A     = (u16*)(smem + OFF_A);
  u16*   W1    = (u16*)(smem + OFF_W1);
  float* partf = (float*)(smem + OFF_PART);
  float* netp  = (float*)(smem + OFF_NETP);
  float* mrsA  = (float*)(smem + OFF_MRS);
  float* dts   = (float*)(smem + OFF_DTS);

  const int tid  = threadIdx.x;
  const int wave = tid >> 6;
  const int lane = tid & 63;
  const int q    = lane >> 4;
  const int c15  = lane & 15;
  const int l32  = lane & 31;
  const int cg   = wave;
  const int colbase = cg * 32;
  const int s0 = blockIdx.x * 32;
  const bool oddl = (c15 & 1);
  const u32  xsel = oddl ? 0x07060302u : 0x01000504u;   // perm(own, partner, xsel)

  // ---- staging ----
  for (int idx = tid; idx < 8192; idx += NTHREADS){
    int n = idx >> 5, ch = idx & 31;
    *(v8s*)(W1 + n*AROW + ch*8) = *(const v8s*)(ws + WS_W1 + n*256 + ch*8);
  }
  if (tid < NSTEP) dts[tid] = t_span[tid+1] - t_span[tid];

  // ---- RK4 state: every lane mirrors sample (lane&31) ----
  float yc0,yc1,yc2, ys0,ys1,ys2, su0=0,su1=0,su2=0, Om,P1,ga;
  {
    int s = l32;
    yc0 = y0g[(s0+s)*3+0]; yc1 = y0g[(s0+s)*3+1]; yc2 = y0g[(s0+s)*3+2];
    Om  = params[(s0+s)*3+0]; P1 = params[(s0+s)*3+1]; ga = params[(s0+s)*3+2];
    ys0 = yc0; ys1 = yc1; ys2 = yc2;
    if (wave == 0 && lane < 32){
      out[(s0+s)*3+0] = yc0; out[(s0+s)*3+1] = yc1; out[(s0+s)*3+2] = yc2;
    }
  }
  const float gate = gatep[0];
  const float bo0 = boutg[0], bo1 = boutg[1], bo2 = boutg[2];

  // ---- persistent registers ----
  v8s w0f[2];
#pragma unroll
  for (int nt = 0; nt < 2; ++nt)
    w0f[nt] = *(const v8s*)(ws + WS_W0 + (q*256 + colbase + nt*16 + c15)*8);

  v8s wf[2][8][2];   // W2,W3 fragments (AGPR-resident)
#pragma unroll
  for (int l = 0; l < 2; ++l)
#pragma unroll
    for (int nt = 0; nt < 2; ++nt)
#pragma unroll
      for (int kc = 0; kc < 8; ++kc)
        wf[l][kc][nt] = *(const v8s*)(ws + WS_W23 +
            ((l*4 + q)*256 + colbase + nt*16 + c15)*64 + kc*8);

  float wo[2][3];
#pragma unroll
  for (int nt = 0; nt < 2; ++nt)
#pragma unroll
    for (int o = 0; o < 3; ++o)
      wo[nt][o] = Woutg[(colbase + nt*16 + c15)*3 + o];

  f32x2 lg2[4], lb2[4];
  float bia[3][2];
#pragma unroll
  for (int l = 0; l < 4; ++l){
    int c0 = colbase + c15, c1 = colbase + 16 + c15;
    lg2[l].x = ln_gg[l*H_ + c0]; lg2[l].y = ln_gg[l*H_ + c1];
    lb2[l].x = ln_bg[l*H_ + c0]; lb2[l].y = ln_bg[l*H_ + c1];
    if (l >= 1){ bia[l-1][0] = bhg[(l-1)*H_ + c0]; bia[l-1][1] = bhg[(l-1)*H_ + c1]; }
  }

  const u16* pa = A  + c15*AROW + q*8;
  const u16* pw = W1 + (colbase + c15)*AROW + q*8;
  u16* pst2 = A + colbase + (oddl ? 16 : 0) + (c15 & ~1);   // paired-store base
  float* mymrs = mrsA + wave*64;                            // wave-private stats
  const f32x4 fzero = {0.f,0.f,0.f,0.f};
  const int ba0 = c15 << 2, ba1 = (16 + c15) << 2;

  // layer-0 A-fragments, register-built from RK4 state (no LDS round trip)
  v8s fa0, fa1;
  u32 p2c = permb(__float_as_uint(ga), __float_as_uint(P1), 0x07060302u);  // (P1,ga) const
  auto build_frags = [&](){
    u32 p0 = permb(__float_as_uint(ys1), __float_as_uint(ys0), 0x07060302u);
    u32 p1 = permb(__float_as_uint(Om),  __float_as_uint(ys2), 0x07060302u);
    union { u32 w[4]; v8s v; } f0, f1;
    f0.w[0] = (u32)__builtin_amdgcn_ds_bpermute(ba0, (int)p0);
    f0.w[1] = (u32)__builtin_amdgcn_ds_bpermute(ba0, (int)p1);
    f0.w[2] = (u32)__builtin_amdgcn_ds_bpermute(ba0, (int)p2c);
    f0.w[3] = 0x00003F80u;                                   // (1.0, 0)
    f1.w[0] = (u32)__builtin_amdgcn_ds_bpermute(ba1, (int)p0);
    f1.w[1] = (u32)__builtin_amdgcn_ds_bpermute(ba1, (int)p1);
    f1.w[2] = (u32)__builtin_amdgcn_ds_bpermute(ba1, (int)p2c);
    f1.w[3] = 0x00003F80u;
    fa0 = f0.v; fa1 = f1.v;
  };
  build_frags();

  __syncthreads();

  // LN head: DPP partial reduce -> partf -> barrier -> redundant stats -> wave mrs
  auto ln_head = [&](f32x4 (&acc)[2][2]){
    float rs[2][4], rq[2][4];
#pragma unroll
    for (int mt = 0; mt < 2; ++mt)
#pragma unroll
      for (int r = 0; r < 4; ++r){
        float a0 = acc[mt][0][r], a1 = acc[mt][1][r];
        rs[mt][r] = a0 + a1;
        rq[mt][r] = a0*a0 + a1*a1;
      }
#pragma unroll
    for (int mt = 0; mt < 2; ++mt)
#pragma unroll
      for (int r = 0; r < 4; ++r){
        float s = rs[mt][r], qq = rq[mt][r];
        s = dpp_add<DPP_QP_XOR1>(s);  qq = dpp_add<DPP_QP_XOR1>(qq);
        s = dpp_add<DPP_QP_XOR2>(s);  qq = dpp_add<DPP_QP_XOR2>(qq);
        s = dpp_add<DPP_ROR4>(s);     qq = dpp_add<DPP_ROR4>(qq);
        s = dpp_add<DPP_ROR8>(s);     qq = dpp_add<DPP_ROR8>(qq);
        rs[mt][r] = s; rq[mt][r] = qq;
      }
    if (c15 < 4){
#pragma unroll
      for (int mt = 0; mt < 2; ++mt){
        float sS = (c15==0) ? rs[mt][0] : (c15==1) ? rs[mt][1] : (c15==2) ? rs[mt][2] : rs[mt][3];
        float sQ = (c15==0) ? rq[mt][0] : (c15==1) ? rq[mt][1] : (c15==2) ? rq[mt][2] : rq[mt][3];
        f32x2 v; v.x = sS; v.y = sQ;
        *(f32x2*)(partf + (mt*16 + q*4 + c15)*PWF + cg*2) = v;
      }
    }
    __syncthreads();
    const f32x4* pp = (const f32x4*)(partf + l32*PWF);
    f32x4 p0 = pp[0], p1 = pp[1], p2 = pp[2], p3 = pp[3];
    float S = ((p0[0]+p0[2])+(p1[0]+p1[2]))+((p2[0]+p2[2])+(p3[0]+p3[2]));
    float Q = ((p0[1]+p0[3])+(p1[1]+p1[3]))+((p2[1]+p2[3])+(p3[1]+p3[3]));
    float mean = S * (1.f/256.f);
    float var  = Q * (1.f/256.f) - mean*mean;
    float rstd = rsqrtf(var + 1e-5f);
    if (lane < 32){
      f32x2 mr; mr.x = rstd; mr.y = -mean*rstd;
      *(f32x2*)(mymrs + l32*2) = mr;
    }
  };

  // LN tail + SiLU + paired bf16 store (layers 0..2)
  auto ln_tail = [&](f32x4 (&acc)[2][2], int li){
    f32x2 g2 = lg2[li], b2 = lb2[li];
#pragma unroll
    for (int mt = 0; mt < 2; ++mt)
#pragma unroll
      for (int r = 0; r < 4; ++r){
        f32x2 mr = *(const f32x2*)(mymrs + (mt*16 + q*4 + r)*2);
        f32x2 sc = g2 * mr.x;
        f32x2 of = g2 * mr.y + b2;
        f32x2 av; av.x = acc[mt][0][r]; av.y = acc[mt][1][r];
        f32x2 v  = av * sc + of;
        f32x2 ea = v * (-1.44269504f);
        f32x2 den; den.x = 1.f + __builtin_amdgcn_exp2f(ea.x);
                   den.y = 1.f + __builtin_amdgcn_exp2f(ea.y);
        f32x2 rc; rc.x = __builtin_amdgcn_rcpf(den.x); rc.y = __builtin_amdgcn_rcpf(den.y);
        f32x2 sv = v * rc;
        u32 own = permb(__float_as_uint(sv.y), __float_as_uint(sv.x), 0x07060302u);
        u32 par = dpp_movu<DPP_QP_XOR1>(own);
        u32 word = permb(own, par, xsel);
        *(u32*)(pst2 + (mt*16 + q*4 + r)*AROW) = word;
      }
    __syncthreads();
  };

#pragma unroll 1
  for (int step = 0; step < NSTEP; ++step){
    float dt = dts[step];
#pragma unroll 1
    for (int stage = 0; stage < 4; ++stage){
      f32x4 acc[2][2];

      // ---- layer 0: register-built frags (K=32; bias row folded into W0) ----
#pragma unroll
      for (int mt = 0; mt < 2; ++mt){ acc[mt][0] = fzero; acc[mt][1] = fzero; }
      acc[0][0] = MFMA16(fa0, w0f[0], acc[0][0]);
      acc[0][1] = MFMA16(fa0, w0f[1], acc[0][1]);
      acc[1][0] = MFMA16(fa1, w0f[0], acc[1][0]);
      acc[1][1] = MFMA16(fa1, w0f[1], acc[1][1]);
      ln_head(acc);
      ln_tail(acc, 0);

      // ---- layer 1: W1 from LDS (acc init = bias) ----
#pragma unroll
      for (int mt = 0; mt < 2; ++mt)
#pragma unroll
        for (int nt = 0; nt < 2; ++nt){
          float b = bia[0][nt];
          f32x4 bb; bb[0]=b; bb[1]=b; bb[2]=b; bb[3]=b;
          acc[mt][nt] = bb;
        }
#pragma unroll
      for (int kc = 0; kc < 8; ++kc){
        v8s a0  = *(const v8s*)(pa + kc*32);
        v8s a1  = *(const v8s*)(pa + 16*AROW + kc*32);
        v8s b0f = *(const v8s*)(pw + kc*32);
        v8s b1f = *(const v8s*)(pw + 16*AROW + kc*32);
        acc[0][0] = MFMA16(a0, b0f, acc[0][0]);
        acc[0][1] = MFMA16(a0, b1f, acc[0][1]);
        acc[1][0] = MFMA16(a1, b0f, acc[1][0]);
        acc[1][1] = MFMA16(a1, b1f, acc[1][1]);
      }
      ln_head(acc);
      ln_tail(acc, 1);

      // ---- layers 2,3: W from registers (acc init = bias) ----
#pragma unroll 1
      for (int l = 0; l < 2; ++l){
#pragma unroll
        for (int mt = 0; mt < 2; ++mt)
#pragma unroll
          for (int nt = 0; nt < 2; ++nt){
            float b = bia[1+l][nt];
            f32x4 bb; bb[0]=b; bb[1]=b; bb[2]=b; bb[3]=b;
            acc[mt][nt] = bb;
          }
#pragma unroll
        for (int kc = 0; kc < 8; ++kc){
          v8s a0 = *(const v8s*)(pa + kc*32);
          v8s a1 = *(const v8s*)(pa + 16*AROW + kc*32);
          acc[0][0] = MFMA16(a0, wf[l][kc][0], acc[0][0]);
          acc[0][1] = MFMA16(a0, wf[l][kc][1], acc[0][1]);
          acc[1][0] = MFMA16(a1, wf[l][kc][0], acc[1][0]);
          acc[1][1] = MFMA16(a1, wf[l][kc][1], acc[1][1]);
        }
        if (l == 0){ ln_head(acc); ln_tail(acc, 2); }
      }

      // ---- ln3 + fused fp32 output layer ----
      {
        ln_head(acc);
        f32x2 g2 = lg2[3], b2 = lb2[3];
#pragma unroll
        for (int mt = 0; mt < 2; ++mt)
#pragma unroll
          for (int r = 0; r < 4; ++r){
            f32x2 mr = *(const f32x2*)(mymrs + (mt*16 + q*4 + r)*2);
            f32x2 sc = g2 * mr.x;
            f32x2 of = g2 * mr.y + b2;
            f32x2 av; av.x = acc[mt][0][r]; av.y = acc[mt][1][r];
            f32x2 v  = av * sc + of;
            f32x2 ea = v * (-1.44269504f);
            f32x2 den; den.x = 1.f + __builtin_amdgcn_exp2f(ea.x);
                       den.y = 1.f + __builtin_amdgcn_exp2f(ea.y);
            f32x2 rc; rc.x = __builtin_amdgcn_rcpf(den.x); rc.y = __builtin_amdgcn_rcpf(den.y);
            f32x2 sv = v * rc;
            float po0 = sv.x*wo[0][0] + sv.y*wo[1][0];
            float po1 = sv.x*wo[0][1] + sv.y*wo[1][1];
            float po2 = sv.x*wo[0][2] + sv.y*wo[1][2];
            po0 = dpp_add<DPP_QP_XOR1>(po0); po1 = dpp_add<DPP_QP_XOR1>(po1); po2 = dpp_add<DPP_QP_XOR1>(po2);
            po0 = dpp_add<DPP_QP_XOR2>(po0); po1 = dpp_add<DPP_QP_XOR2>(po1); po2 = dpp_add<DPP_QP_XOR2>(po2);
            po0 = dpp_add<DPP_ROR4>(po0);    po1 = dpp_add<DPP_ROR4>(po1);    po2 = dpp_add<DPP_ROR4>(po2);
            po0 = dpp_add<DPP_ROR8>(po0);    po1 = dpp_add<DPP_ROR8>(po1);    po2 = dpp_add<DPP_ROR8>(po2);
            if (c15 == 0){
              f32x4 st; st[0] = po0; st[1] = po1; st[2] = po2; st[3] = 0.f;
              *(f32x4*)(netp + (cg*32 + mt*16 + q*4 + r)*4) = st;
            }
          }
      }
      __syncthreads();

      // ---- RK4, redundant in all waves (state per lane, sample = lane&31) ----
      {
        int s = l32;
        float n0 = 0.f, n1 = 0.f, n2 = 0.f;
#pragma unroll
        for (int c = 0; c < 8; ++c){
          f32x4 v = *(const f32x4*)(netp + (c*32 + s)*4);
          n0 += v[0]; n1 += v[1]; n2 += v[2];
        }
        float k0 = -ga*ys0                      + gate*(n0 + bo0);
        float k1 = -ga*ys1 - Om*ys2             + gate*(n1 + bo1);
        float k2 = -2.f*ga*(ys2 + 1.f) + Om*ys1 + gate*(n2 + bo2);
        if (stage == 0){
          su0 = yc0 + dt*(1.f/6.f)*k0; su1 = yc1 + dt*(1.f/6.f)*k1; su2 = yc2 + dt*(1.f/6.f)*k2;
          ys0 = yc0 + 0.5f*dt*k0; ys1 = yc1 + 0.5f*dt*k1; ys2 = yc2 + 0.5f*dt*k2;
        } else if (stage == 1){
          su0 += dt*(1.f/3.f)*k0; su1 += dt*(1.f/3.f)*k1; su2 += dt*(1.f/3.f)*k2;
          ys0 = yc0 + 0.5f*dt*k0; ys1 = yc1 + 0.5f*dt*k1; ys2 = yc2 + 0.5f*dt*k2;
        } else if (stage == 2){
          su0 += dt*(1.f/3.f)*k0; su1 += dt*(1.f/3.f)*k1; su2 += dt*(1.f/3.f)*k2;
          ys0 = yc0 + dt*k0; ys1 = yc1 + dt*k1; ys2 = yc2 + dt*k2;
        } else {
          yc0 = su0 + dt*(1.f/6.f)*k0; yc1 = su1 + dt*(1.f/6.f)*k1; yc2 = su2 + dt*(1.f/6.f)*k2;
          ys0 = yc0; ys1 = yc1; ys2 = yc2;
          if (wave == 0 && lane < 32){
            out[(step+1)*(B_*3) + (s0+s)*3 + 0] = yc0;
            out[(step+1)*(B_*3) + (s0+s)*3 + 1] = yc1;
            out[(step+1)*(B_*3) + (s0+s)*3 + 2] = yc2;
          }
        }
        build_frags();   // next stage's layer-0 input, in registers
      }
      // no barrier needed: layer-0 reads registers; partf/A writes are fenced above
    }
  }
}

extern "C" void kernel_launch(void* const* d_in, const int* in_sizes, int n_in,
                              void* d_out, int out_size, void* d_ws, size_t ws_size,
                              hipStream_t stream) {
  const float* y0     = (const float*)d_in[0];
  const float* t_span = (const float*)d_in[1];
  const float* params = (const float*)d_in[2];
  const float* W0     = (const float*)d_in[3];
  const float* b0     = (const float*)d_in[4];
  const float* Wh     = (const float*)d_in[5];
  const float* bh     = (const float*)d_in[6];
  const float* ln_g   = (const float*)d_in[7];
  const float* ln_b   = (const float*)d_in[8];
  const float* Wout   = (const float*)d_in[9];
  const float* bout   = (const float*)d_in[10];
  const float* gate   = (const float*)d_in[11];
  float* out = (float*)d_out;
  u16* ws = (u16*)d_ws;

  prep_kernel<<<WS_TOT/256, 256, 0, stream>>>(W0, b0, Wh, ws);

  hipFuncSetAttribute(reinterpret_cast<const void*>(pinode_kernel),
                      hipFuncAttributeMaxDynamicSharedMemorySize, LDS_TOTAL);
  pinode_kernel<<<NBLOCKS, NTHREADS, LDS_TOTAL, stream>>>(
      y0, t_span, params, bh, ln_g, ln_b, bout, gate, Wout, ws, out);
}

// Round 7
// 1390.416 us; speedup vs baseline: 1.4837x; 1.4837x over previous
//
#include <hip/hip_runtime.h>

typedef unsigned short u16;
typedef unsigned int   u32;
typedef short v8s   __attribute__((ext_vector_type(8)));
typedef float f32x4 __attribute__((ext_vector_type(4)));
typedef float f32x2 __attribute__((ext_vector_type(2)));

#define H_ 256
#define B_ 8192
#define NSTEP 31
#define NTHREADS 512
#define NBLOCKS 256
#define AROW 264   // 256+8 u16 pad: 528B rows

#define MFMA16(a,b,c) __builtin_amdgcn_mfma_f32_16x16x32_bf16(a,b,c,0,0,0)

#define DPP_QP_XOR1 0xB1
#define DPP_QP_XOR2 0x4E
#define DPP_ROR4    0x124
#define DPP_ROR8    0x128

template<int CTRL>
__device__ __forceinline__ float dpp_add(float v){
  return v + __int_as_float(__builtin_amdgcn_update_dpp(0, __float_as_int(v), CTRL, 0xF, 0xF, true));
}
template<int CTRL>
__device__ __forceinline__ u32 dpp_movu(u32 v){
  return (u32)__builtin_amdgcn_update_dpp(0, (int)v, CTRL, 0xF, 0xF, true);
}
__device__ __forceinline__ u32 permb(u32 a, u32 b, u32 sel){
  return __builtin_amdgcn_perm(a, b, sel);
}
__device__ __forceinline__ u16 f2bf_rne(float f){
  unsigned u = __float_as_uint(f);
  u += 0x7fffu + ((u >> 16) & 1u);
  return (u16)(u >> 16);
}

// ---- workspace (u16 units) ----
#define WS_W0   0        // [q][n][j] 4*256*8 = 8192 (K-pad to 32; k==6 row = b0)
#define WS_W1   8192     // [n][k]   256*256 = 65536 (Wh[0] transposed)
#define WS_W23  73728    // [l][q][col][kc][j] 2*4*256*64 = 131072
#define WS_TOT  204800

__global__ void prep_kernel(const float* __restrict__ W0,
                            const float* __restrict__ b0,
                            const float* __restrict__ Wh,
                            u16* __restrict__ ws){
  int i = blockIdx.x * 256 + threadIdx.x;
  if (i < 8192){
    int q = i >> 11, n = (i >> 3) & 255, j = i & 7;
    int k = q*8 + j;
    float v = (k < 6) ? W0[k*H_ + n] : ((k == 6) ? b0[n] : 0.f);
    ws[i] = f2bf_rne(v);
  } else if (i < 73728){
    int r = i - 8192;
    int n = r >> 8, k = r & 255;
    ws[i] = f2bf_rne(Wh[k*H_ + n]);
  } else if (i < WS_TOT){
    int r = i - 73728;
    int j = r & 7, kc = (r >> 3) & 7, col = (r >> 6) & 255;
    int q = (r >> 14) & 3, l = (r >> 16) & 1;
    int k = kc*32 + q*8 + j;
    ws[i] = f2bf_rne(Wh[(1 + l)*H_*H_ + k*H_ + col]);
  }
}

// ---- LDS (bytes) ----
#define PWF 20
#define OFF_A      0        // 16896
#define OFF_W1     16896    // 135168
#define OFF_PART   152064   // 32*PWF*4 = 2560
#define OFF_NETP   154624   // 8*32*16 = 4096
#define OFF_MRS    158720   // 8 waves * 32 rows * 8B = 2048
#define OFF_DTS    160768   // 128
#define LDS_TOTAL  160896

__global__ __launch_bounds__(NTHREADS, 2)
void pinode_kernel(const float* __restrict__ y0g, const float* __restrict__ t_span,
                   const float* __restrict__ params, const float* __restrict__ bhg,
                   const float* __restrict__ ln_gg, const float* __restrict__ ln_bg,
                   const float* __restrict__ boutg, const float* __restrict__ gatep,
                   const float* __restrict__ Woutg, const u16* __restrict__ ws,
                   float* __restrict__ out)
{
  extern __shared__ char smem[];
  u16*   A     = (u16*)(smem + OFF_A);
  u16*   W1    = (u16*)(smem + OFF_W1);
  float* partf = (float*)(smem + OFF_PART);
  float* netp  = (float*)(smem + OFF_NETP);
  float* mrsA  = (float*)(smem + OFF_MRS);
  float* dts   = (float*)(smem + OFF_DTS);

  const int tid  = threadIdx.x;
  const int wave = tid >> 6;
  const int lane = tid & 63;
  const int q    = lane >> 4;
  const int c15  = lane & 15;
  const int l32  = lane & 31;
  const int cg   = wave;
  const int colbase = cg * 32;
  const int s0 = blockIdx.x * 32;
  const bool oddl = (c15 & 1);
  const u32  xsel = oddl ? 0x07060302u : 0x01000504u;   // perm(own, partner, xsel)

  // ---- staging ----
  for (int idx = tid; idx < 8192; idx += NTHREADS){
    int n = idx >> 5, ch = idx & 31;
    *(v8s*)(W1 + n*AROW + ch*8) = *(const v8s*)(ws + WS_W1 + n*256 + ch*8);
  }
  if (tid < NSTEP) dts[tid] = t_span[tid+1] - t_span[tid];

  // ---- RK4 state: every lane mirrors sample (lane&31) ----
  float yc0,yc1,yc2, ys0,ys1,ys2, su0=0,su1=0,su2=0, Om,P1,ga;
  {
    int s = l32;
    yc0 = y0g[(s0+s)*3+0]; yc1 = y0g[(s0+s)*3+1]; yc2 = y0g[(s0+s)*3+2];
    Om  = params[(s0+s)*3+0]; P1 = params[(s0+s)*3+1]; ga = params[(s0+s)*3+2];
    ys0 = yc0; ys1 = yc1; ys2 = yc2;
    if (wave == 0 && lane < 32){
      out[(s0+s)*3+0] = yc0; out[(s0+s)*3+1] = yc1; out[(s0+s)*3+2] = yc2;
    }
  }
  const float gate = gatep[0];
  const float bo0 = boutg[0], bo1 = boutg[1], bo2 = boutg[2];

  // ---- persistent registers ----
  v8s w0f[2];
#pragma unroll
  for (int nt = 0; nt < 2; ++nt)
    w0f[nt] = *(const v8s*)(ws + WS_W0 + (q*256 + colbase + nt*16 + c15)*8);

  v8s wf[2][8][2];   // W2,W3 fragments (AGPR-resident; MUST stay fully unrolled)
#pragma unroll
  for (int l = 0; l < 2; ++l)
#pragma unroll
    for (int nt = 0; nt < 2; ++nt)
#pragma unroll
      for (int kc = 0; kc < 8; ++kc)
        wf[l][kc][nt] = *(const v8s*)(ws + WS_W23 +
            ((l*4 + q)*256 + colbase + nt*16 + c15)*64 + kc*8);

  float wo[2][3];
#pragma unroll
  for (int nt = 0; nt < 2; ++nt)
#pragma unroll
    for (int o = 0; o < 3; ++o)
      wo[nt][o] = Woutg[(colbase + nt*16 + c15)*3 + o];

  f32x2 lg2[4], lb2[4];
  float bia[3][2];
#pragma unroll
  for (int l = 0; l < 4; ++l){
    int c0 = colbase + c15, c1 = colbase + 16 + c15;
    lg2[l].x = ln_gg[l*H_ + c0]; lg2[l].y = ln_gg[l*H_ + c1];
    lb2[l].x = ln_bg[l*H_ + c0]; lb2[l].y = ln_bg[l*H_ + c1];
    if (l >= 1){ bia[l-1][0] = bhg[(l-1)*H_ + c0]; bia[l-1][1] = bhg[(l-1)*H_ + c1]; }
  }

  const u16* pa = A  + c15*AROW + q*8;
  const u16* pw = W1 + (colbase + c15)*AROW + q*8;
  u16* pst2 = A + colbase + (oddl ? 16 : 0) + (c15 & ~1);   // paired-store base
  float* mymrs = mrsA + wave*64;                            // wave-private stats
  const f32x4 fzero = {0.f,0.f,0.f,0.f};
  const int ba0 = c15 << 2, ba1 = (16 + c15) << 2;

  // layer-0 A-fragments, register-built from RK4 state (no LDS round trip)
  v8s fa0, fa1;
  u32 p2c = permb(__float_as_uint(ga), __float_as_uint(P1), 0x07060302u);  // (P1,ga) const
  auto build_frags = [&](){
    u32 p0 = permb(__float_as_uint(ys1), __float_as_uint(ys0), 0x07060302u);
    u32 p1 = permb(__float_as_uint(Om),  __float_as_uint(ys2), 0x07060302u);
    union { u32 w[4]; v8s v; } f0, f1;
    f0.w[0] = (u32)__builtin_amdgcn_ds_bpermute(ba0, (int)p0);
    f0.w[1] = (u32)__builtin_amdgcn_ds_bpermute(ba0, (int)p1);
    f0.w[2] = (u32)__builtin_amdgcn_ds_bpermute(ba0, (int)p2c);
    f0.w[3] = 0x00003F80u;                                   // (1.0, 0)
    f1.w[0] = (u32)__builtin_amdgcn_ds_bpermute(ba1, (int)p0);
    f1.w[1] = (u32)__builtin_amdgcn_ds_bpermute(ba1, (int)p1);
    f1.w[2] = (u32)__builtin_amdgcn_ds_bpermute(ba1, (int)p2c);
    f1.w[3] = 0x00003F80u;
    fa0 = f0.v; fa1 = f1.v;
  };
  build_frags();

  __syncthreads();

  // LN head: DPP partial reduce -> partf -> barrier -> redundant stats -> wave mrs
  auto ln_head = [&](f32x4 (&acc)[2][2]){
    float rs[2][4], rq[2][4];
#pragma unroll
    for (int mt = 0; mt < 2; ++mt)
#pragma unroll
      for (int r = 0; r < 4; ++r){
        float a0 = acc[mt][0][r], a1 = acc[mt][1][r];
        rs[mt][r] = a0 + a1;
        rq[mt][r] = a0*a0 + a1*a1;
      }
#pragma unroll
    for (int mt = 0; mt < 2; ++mt)
#pragma unroll
      for (int r = 0; r < 4; ++r){
        float s = rs[mt][r], qq = rq[mt][r];
        s = dpp_add<DPP_QP_XOR1>(s);  qq = dpp_add<DPP_QP_XOR1>(qq);
        s = dpp_add<DPP_QP_XOR2>(s);  qq = dpp_add<DPP_QP_XOR2>(qq);
        s = dpp_add<DPP_ROR4>(s);     qq = dpp_add<DPP_ROR4>(qq);
        s = dpp_add<DPP_ROR8>(s);     qq = dpp_add<DPP_ROR8>(qq);
        rs[mt][r] = s; rq[mt][r] = qq;
      }
    if (c15 < 4){
#pragma unroll
      for (int mt = 0; mt < 2; ++mt){
        float sS = (c15==0) ? rs[mt][0] : (c15==1) ? rs[mt][1] : (c15==2) ? rs[mt][2] : rs[mt][3];
        float sQ = (c15==0) ? rq[mt][0] : (c15==1) ? rq[mt][1] : (c15==2) ? rq[mt][2] : rq[mt][3];
        f32x2 v; v.x = sS; v.y = sQ;
        *(f32x2*)(partf + (mt*16 + q*4 + c15)*PWF + cg*2) = v;
      }
    }
    __syncthreads();
    const f32x4* pp = (const f32x4*)(partf + l32*PWF);
    f32x4 p0 = pp[0], p1 = pp[1], p2 = pp[2], p3 = pp[3];
    float S = ((p0[0]+p0[2])+(p1[0]+p1[2]))+((p2[0]+p2[2])+(p3[0]+p3[2]));
    float Q = ((p0[1]+p0[3])+(p1[1]+p1[3]))+((p2[1]+p2[3])+(p3[1]+p3[3]));
    float mean = S * (1.f/256.f);
    float var  = Q * (1.f/256.f) - mean*mean;
    float rstd = rsqrtf(var + 1e-5f);
    if (lane < 32){
      f32x2 mr; mr.x = rstd; mr.y = -mean*rstd;
      *(f32x2*)(mymrs + l32*2) = mr;
    }
  };

  // LN tail + SiLU + paired bf16 store (layers 0..2)
  auto ln_tail = [&](f32x4 (&acc)[2][2], int li){
    f32x2 g2 = lg2[li], b2 = lb2[li];
#pragma unroll
    for (int mt = 0; mt < 2; ++mt)
#pragma unroll
      for (int r = 0; r < 4; ++r){
        f32x2 mr = *(const f32x2*)(mymrs + (mt*16 + q*4 + r)*2);
        f32x2 sc = g2 * mr.x;
        f32x2 of = g2 * mr.y + b2;
        f32x2 av; av.x = acc[mt][0][r]; av.y = acc[mt][1][r];
        f32x2 v  = av * sc + of;
        f32x2 ea = v * (-1.44269504f);
        f32x2 den; den.x = 1.f + __builtin_amdgcn_exp2f(ea.x);
                   den.y = 1.f + __builtin_amdgcn_exp2f(ea.y);
        f32x2 rc; rc.x = __builtin_amdgcn_rcpf(den.x); rc.y = __builtin_amdgcn_rcpf(den.y);
        f32x2 sv = v * rc;
        u32 own = permb(__float_as_uint(sv.y), __float_as_uint(sv.x), 0x07060302u);
        u32 par = dpp_movu<DPP_QP_XOR1>(own);
        u32 word = permb(own, par, xsel);
        *(u32*)(pst2 + (mt*16 + q*4 + r)*AROW) = word;
      }
    __syncthreads();
  };

#pragma unroll 1
  for (int step = 0; step < NSTEP; ++step){
    float dt = dts[step];
#pragma unroll 1
    for (int stage = 0; stage < 4; ++stage){
      f32x4 acc[2][2];

      // ---- layer 0: register-built frags (K=32; bias row folded into W0) ----
#pragma unroll
      for (int mt = 0; mt < 2; ++mt){ acc[mt][0] = fzero; acc[mt][1] = fzero; }
      acc[0][0] = MFMA16(fa0, w0f[0], acc[0][0]);
      acc[0][1] = MFMA16(fa0, w0f[1], acc[0][1]);
      acc[1][0] = MFMA16(fa1, w0f[0], acc[1][0]);
      acc[1][1] = MFMA16(fa1, w0f[1], acc[1][1]);
      ln_head(acc);
      ln_tail(acc, 0);

      // ---- layer 1: W1 from LDS (acc init = bias) ----
#pragma unroll
      for (int mt = 0; mt < 2; ++mt)
#pragma unroll
        for (int nt = 0; nt < 2; ++nt){
          float b = bia[0][nt];
          f32x4 bb; bb[0]=b; bb[1]=b; bb[2]=b; bb[3]=b;
          acc[mt][nt] = bb;
        }
#pragma unroll
      for (int kc = 0; kc < 8; ++kc){
        v8s a0  = *(const v8s*)(pa + kc*32);
        v8s a1  = *(const v8s*)(pa + 16*AROW + kc*32);
        v8s b0f = *(const v8s*)(pw + kc*32);
        v8s b1f = *(const v8s*)(pw + 16*AROW + kc*32);
        acc[0][0] = MFMA16(a0, b0f, acc[0][0]);
        acc[0][1] = MFMA16(a0, b1f, acc[0][1]);
        acc[1][0] = MFMA16(a1, b0f, acc[1][0]);
        acc[1][1] = MFMA16(a1, b1f, acc[1][1]);
      }
      ln_head(acc);
      ln_tail(acc, 1);

      // ---- layers 2,3: W from registers (acc init = bias); FULL unroll (wf must
      //      stay register-indexed — '#pragma unroll 1' here caused the R6 spill) ----
#pragma unroll
      for (int l = 0; l < 2; ++l){
#pragma unroll
        for (int mt = 0; mt < 2; ++mt)
#pragma unroll
          for (int nt = 0; nt < 2; ++nt){
            float b = bia[1+l][nt];
            f32x4 bb; bb[0]=b; bb[1]=b; bb[2]=b; bb[3]=b;
            acc[mt][nt] = bb;
          }
#pragma unroll
        for (int kc = 0; kc < 8; ++kc){
          v8s a0 = *(const v8s*)(pa + kc*32);
          v8s a1 = *(const v8s*)(pa + 16*AROW + kc*32);
          acc[0][0] = MFMA16(a0, wf[l][kc][0], acc[0][0]);
          acc[0][1] = MFMA16(a0, wf[l][kc][1], acc[0][1]);
          acc[1][0] = MFMA16(a1, wf[l][kc][0], acc[1][0]);
          acc[1][1] = MFMA16(a1, wf[l][kc][1], acc[1][1]);
        }
        if (l == 0){ ln_head(acc); ln_tail(acc, 2); }
      }

      // ---- ln3 + fused fp32 output layer ----
      {
        ln_head(acc);
        f32x2 g2 = lg2[3], b2 = lb2[3];
#pragma unroll
        for (int mt = 0; mt < 2; ++mt)
#pragma unroll
          for (int r = 0; r < 4; ++r){
            f32x2 mr = *(const f32x2*)(mymrs + (mt*16 + q*4 + r)*2);
            f32x2 sc = g2 * mr.x;
            f32x2 of = g2 * mr.y + b2;
            f32x2 av; av.x = acc[mt][0][r]; av.y = acc[mt][1][r];
            f32x2 v  = av * sc + of;
            f32x2 ea = v * (-1.44269504f);
            f32x2 den; den.x = 1.f + __builtin_amdgcn_exp2f(ea.x);
                       den.y = 1.f + __builtin_amdgcn_exp2f(ea.y);
            f32x2 rc; rc.x = __builtin_amdgcn_rcpf(den.x); rc.y = __builtin_amdgcn_rcpf(den.y);
            f32x2 sv = v * rc;
            float po0 = sv.x*wo[0][0] + sv.y*wo[1][0];
            float po1 = sv.x*wo[0][1] + sv.y*wo[1][1];
            float po2 = sv.x*wo[0][2] + sv.y*wo[1][2];
            po0 = dpp_add<DPP_QP_XOR1>(po0); po1 = dpp_add<DPP_QP_XOR1>(po1); po2 = dpp_add<DPP_QP_XOR1>(po2);
            po0 = dpp_add<DPP_QP_XOR2>(po0); po1 = dpp_add<DPP_QP_XOR2>(po1); po2 = dpp_add<DPP_QP_XOR2>(po2);
            po0 = dpp_add<DPP_ROR4>(po0);    po1 = dpp_add<DPP_ROR4>(po1);    po2 = dpp_add<DPP_ROR4>(po2);
            po0 = dpp_add<DPP_ROR8>(po0);    po1 = dpp_add<DPP_ROR8>(po1);    po2 = dpp_add<DPP_ROR8>(po2);
            if (c15 == 0){
              f32x4 st; st[0] = po0; st[1] = po1; st[2] = po2; st[3] = 0.f;
              *(f32x4*)(netp + (cg*32 + mt*16 + q*4 + r)*4) = st;
            }
          }
      }
      __syncthreads();

      // ---- RK4, redundant in all waves (state per lane, sample = lane&31) ----
      {
        int s = l32;
        float n0 = 0.f, n1 = 0.f, n2 = 0.f;
#pragma unroll
        for (int c = 0; c < 8; ++c){
          f32x4 v = *(const f32x4*)(netp + (c*32 + s)*4);
          n0 += v[0]; n1 += v[1]; n2 += v[2];
        }
        float k0 = -ga*ys0                      + gate*(n0 + bo0);
        float k1 = -ga*ys1 - Om*ys2             + gate*(n1 + bo1);
        float k2 = -2.f*ga*(ys2 + 1.f) + Om*ys1 + gate*(n2 + bo2);
        if (stage == 0){
          su0 = yc0 + dt*(1.f/6.f)*k0; su1 = yc1 + dt*(1.f/6.f)*k1; su2 = yc2 + dt*(1.f/6.f)*k2;
          ys0 = yc0 + 0.5f*dt*k0; ys1 = yc1 + 0.5f*dt*k1; ys2 = yc2 + 0.5f*dt*k2;
        } else if (stage == 1){
          su0 += dt*(1.f/3.f)*k0; su1 += dt*(1.f/3.f)*k1; su2 += dt*(1.f/3.f)*k2;
          ys0 = yc0 + 0.5f*dt*k0; ys1 = yc1 + 0.5f*dt*k1; ys2 = yc2 + 0.5f*dt*k2;
        } else if (stage == 2){
          su0 += dt*(1.f/3.f)*k0; su1 += dt*(1.f/3.f)*k1; su2 += dt*(1.f/3.f)*k2;
          ys0 = yc0 + dt*k0; ys1 = yc1 + dt*k1; ys2 = yc2 + dt*k2;
        } else {
          yc0 = su0 + dt*(1.f/6.f)*k0; yc1 = su1 + dt*(1.f/6.f)*k1; yc2 = su2 + dt*(1.f/6.f)*k2;
          ys0 = yc0; ys1 = yc1; ys2 = yc2;
          if (wave == 0 && lane < 32){
            out[(step+1)*(B_*3) + (s0+s)*3 + 0] = yc0;
            out[(step+1)*(B_*3) + (s0+s)*3 + 1] = yc1;
            out[(step+1)*(B_*3) + (s0+s)*3 + 2] = yc2;
          }
        }
        build_frags();   // next stage's layer-0 input, in registers
      }
      // no trailing barrier: layer-0 consumes registers; LDS hazards fenced above
    }
  }
}

extern "C" void kernel_launch(void* const* d_in, const int* in_sizes, int n_in,
                              void* d_out, int out_size, void* d_ws, size_t ws_size,
                              hipStream_t stream) {
  const float* y0     = (const float*)d_in[0];
  const float* t_span = (const float*)d_in[1];
  const float* params = (const float*)d_in[2];
  const float* W0     = (const float*)d_in[3];
  const float* b0     = (const float*)d_in[4];
  const float* Wh     = (const float*)d_in[5];
  const float* bh     = (const float*)d_in[6];
  const float* ln_g   = (const float*)d_in[7];
  const float* ln_b   = (const float*)d_in[8];
  const float* Wout   = (const float*)d_in[9];
  const float* bout   = (const float*)d_in[10];
  const float* gate   = (const float*)d_in[11];
  float* out = (float*)d_out;
  u16* ws = (u16*)d_ws;

  prep_kernel<<<WS_TOT/256, 256, 0, stream>>>(W0, b0, Wh, ws);

  hipFuncSetAttribute(reinterpret_cast<const void*>(pinode_kernel),
                      hipFuncAttributeMaxDynamicSharedMemorySize, LDS_TOTAL);
  pinode_kernel<<<NBLOCKS, NTHREADS, LDS_TOTAL, stream>>>(
      y0, t_span, params, bh, ln_g, ln_b, bout, gate, Wout, ws, out);
}